// Round 9
// baseline (55.100 us; speedup 1.0000x reference)
//
#include <hip/hip_runtime.h>

namespace {

using v2f = __attribute__((ext_vector_type(2))) float;

constexpr int NQ     = 14;
constexpr int NST    = 1 << NQ;
constexpr int BLOCK  = 512;
constexpr int NWAVES = BLOCK / 64;

// ---------------- compile-time GF(2) machinery (verified R2-R8) ----------------
constexpr unsigned cparity(unsigned x){ x^=x>>8; x^=x>>4; x^=x>>2; x^=x>>1; return x&1u; }

struct Mat { unsigned row[NQ]; unsigned col[NQ]; };

constexpr Mat m_after(int nr){
  Mat m{};
  for(int p=0;p<NQ;++p){ m.row[p]=1u<<p; m.col[p]=1u<<p; }
  for(int l=0;l<nr;++l)
    for(int q=0;q<NQ;++q){
      int cq=(q==NQ-1)?NQ-1:q, tq=(q==NQ-1)?0:q+1;
      int Pc=NQ-1-cq, Pt=NQ-1-tq;
      m.row[Pt]^=m.row[Pc]; m.col[Pc]^=m.col[Pt];
    }
  return m;
}

constexpr Mat M1=m_after(1), M2=m_after(2), M3=m_after(3);
constexpr unsigned amask(int q){ return M1.col[NQ-1-q]; }
constexpr unsigned arow (int q){ return M1.row[NQ-1-q]; }
constexpr unsigned bmask(int q){ return M2.col[NQ-1-q]; }
constexpr unsigned brow (int q){ return M2.row[NQ-1-q]; }

constexpr int rank_of(const unsigned* v, int n){
  unsigned a[24]{};
  for(int i=0;i<n;++i) a[i]=v[i];
  int r=0;
  for(int bit=15;bit>=0;--bit){
    int p=-1;
    for(int i=r;i<n;++i){ if((a[i]>>bit)&1){ p=i; break; } }
    if(p<0) continue;
    unsigned t=a[r]; a[r]=a[p]; a[p]=t;
    for(int i=0;i<n;++i) if(i!=r && ((a[i]>>bit)&1)) a[i]^=a[r];
    ++r;
  }
  return r;
}

// ---- per-kernel gate sets: K0 = L1 q0..9; K1 = L1 q10..13 + 6 L2; K2 = 8 L2 ----
struct Sel {
  int picked[6], wq[4], un[4];
  unsigned Gen[3][10];     // 4 reg + 6 lane generators (K2: slots 8,9 = gate-less fillers)
  unsigned Row[3][10];     // role rows per gate slot
  unsigned BlanePi4[6];    // per-j parity for K1's layer-2 lane gates vs its reg gens
  unsigned EJ4[NQ];        // expectation: parity(M3row_w & cjK2[j])
  int lq[3][10][2];        // (layer, qubit) per gate slot
};

constexpr Sel make_sel(){
  Sel S{};
  unsigned cur[24]{}; int nc=0;
  for(int t=0;t<4;++t) cur[nc++]=amask(10+t);
  bool used[14]{}; int picked[14]{}; int np=0;
  for(int q=0;q<14 && np<10;++q){
    cur[nc]=bmask(q);
    if(rank_of(cur,nc+1)==nc+1){ ++nc; picked[np++]=q; used[q]=true; }
  }
  for(int i=0;i<6;++i) S.picked[i]=picked[i];
  for(int i=0;i<4;++i) S.wq[i]=picked[6+i];
  { int nu=0; for(int q=0;q<14;++q) if(!used[q]) S.un[nu++]=q; }
  for(int i=0;i<6;++i){ unsigned m=0;
    for(int t=0;t<4;++t) m |= cparity(brow(picked[i]) & amask(10+t))<<t;
    S.BlanePi4[i]=m; }
  for(int g=0;g<10;++g){ S.Gen[0][g]=amask(g);    S.Row[0][g]=arow(g);    S.lq[0][g][0]=1; S.lq[0][g][1]=g; }
  for(int g=0;g<4;++g) { S.Gen[1][g]=amask(10+g); S.Row[1][g]=arow(10+g); S.lq[1][g][0]=1; S.lq[1][g][1]=10+g; }
  for(int g=0;g<6;++g) { S.Gen[1][4+g]=bmask(picked[g]); S.Row[1][4+g]=brow(picked[g]);
                         S.lq[1][4+g][0]=2; S.lq[1][4+g][1]=picked[g]; }
  for(int g=0;g<4;++g) { S.Gen[2][g]=bmask(S.wq[g]); S.Row[2][g]=brow(S.wq[g]);
                         S.lq[2][g][0]=2; S.lq[2][g][1]=S.wq[g]; }
  for(int g=0;g<4;++g) { S.Gen[2][4+g]=bmask(S.un[g]); S.Row[2][4+g]=brow(S.un[g]);
                         S.lq[2][4+g][0]=2; S.lq[2][4+g][1]=S.un[g]; }
  // complete K2's gens to rank 10 with unit vectors (layout-only lane dims 4,5 - no gates)
  { unsigned cc[24]{}; int n=0;
    for(int t=0;t<8;++t) cc[n++]=S.Gen[2][t];
    int pos=8;
    for(int p=0;p<14 && pos<10;++p){
      cc[n]=1u<<p;
      if(rank_of(cc,n+1)==n+1){ S.Gen[2][pos]=1u<<p; S.Row[2][pos]=0; ++n; ++pos; }
    } }
  for(int w=0;w<NQ;++w){
    unsigned R=M3.row[NQ-1-w]; unsigned mj=0;
    for(int t=0;t<4;++t) mj |= cparity(R & S.Gen[2][t])<<t;
    S.EJ4[w]=mj;
  }
  return S;
}
constexpr Sel SL = make_sel();
static_assert(rank_of(SL.Gen[0],10)==10, "K0 gens");
static_assert(rank_of(SL.Gen[1],10)==10, "K1 gens");
static_assert(rank_of(SL.Gen[2],10)==10, "K2 gens");

// coset transversal: reps have ZERO at the 10 pivot positions of span(Gen);
// rep(e) = insert e's 4 bits at the non-pivot positions (no parity fills).
struct Ins { unsigned ins[10]; };
constexpr Ins make_ins(const unsigned* gen){
  unsigned a[10]{}; for(int i=0;i<10;++i) a[i]=gen[i];
  int piv[10]{}; int r=0;
  for(int bit=13;bit>=0;--bit){
    int p=-1;
    for(int i=r;i<10;++i){ if((a[i]>>bit)&1){ p=i; break; } }
    if(p<0) continue;
    unsigned t=a[r]; a[r]=a[p]; a[p]=t;
    for(int i=0;i<10;++i) if(i!=r && ((a[i]>>bit)&1)) a[i]^=a[r];
    piv[r++]=bit;
  }
  for(int i=0;i<10;++i) for(int j=i+1;j<10;++j)
    if(piv[j]<piv[i]){ int t=piv[i]; piv[i]=piv[j]; piv[j]=t; }
  Ins I{};
  for(int g=0;g<10;++g) I.ins[g]=(1u<<piv[g])-1u;
  return I;
}
constexpr Ins INS0=make_ins(SL.Gen[0]), INS1=make_ins(SL.Gen[1]), INS2=make_ins(SL.Gen[2]);

struct CJ16 { unsigned v[16]; };
constexpr CJ16 make_cj(const unsigned* gen){
  CJ16 c{};
  for(int j=0;j<16;++j){ unsigned s=0; for(int b=0;b<4;++b) if((j>>b)&1) s^=gen[b]; c.v[j]=s; }
  return c;
}
constexpr CJ16 CJ0=make_cj(SL.Gen[0]), CJ1=make_cj(SL.Gen[1]), CJ2=make_cj(SL.Gen[2]);

// ---------------- packed-f32 complex helpers (verified) ----------------
__device__ __forceinline__ v2f mkv(float a, float b){ v2f r; r[0]=a; r[1]=b; return r; }

__device__ __forceinline__ v2f pk_mul(v2f a, v2f b){
  v2f d; asm("v_pk_mul_f32 %0, %1, %2 op_sel:[0,0] op_sel_hi:[1,1]" : "=v"(d) : "v"(a), "v"(b)); return d;
}
__device__ __forceinline__ v2f pk_fma(v2f a, v2f b, v2f c){
  v2f d; asm("v_pk_fma_f32 %0, %1, %2, %3 op_sel:[0,0,0] op_sel_hi:[1,1,1]" : "=v"(d) : "v"(a), "v"(b), "v"(c)); return d;
}
__device__ __forceinline__ v2f pk_fma_swap1(v2f a, v2f b, v2f c){
  v2f d; asm("v_pk_fma_f32 %0, %1, %2, %3 op_sel:[0,1,0] op_sel_hi:[1,0,1]" : "=v"(d) : "v"(a), "v"(b), "v"(c)); return d;
}
__device__ __forceinline__ v2f cmul_pk(v2f uxx, v2f uyn, v2f s){ return pk_fma_swap1(uyn, s, pk_mul(uxx, s)); }
__device__ __forceinline__ v2f cfma_pk(v2f uxx, v2f uyn, v2f s, v2f acc){ return pk_fma_swap1(uyn, s, pk_fma(uxx, s, acc)); }

__device__ __forceinline__ float2 cmulf(float2 a, float2 b){
  return make_float2(a.x*b.x - a.y*b.y, a.x*b.y + a.y*b.x);
}
__device__ __forceinline__ v2f sel2(bool c, v2f x, v2f y){ v2f r; r[0]=c?x[0]:y[0]; r[1]=c?x[1]:y[1]; return r; }

struct GC { v2f u00x,u00n,u01x,u01n,u10x,u10n,u11x,u11n; };
__device__ __forceinline__ GC load_gc(const v2f* __restrict__ g){
  GC c{g[0],g[1],g[2],g[3],g[4],g[5],g[6],g[7]}; return c;
}

// ---- lane exchange (all variants HW-verified in the passing R7/R8 builds) ----
template<int CTRL>
__device__ __forceinline__ int dpp(int x){
  return __builtin_amdgcn_update_dpp(0, x, CTRL, 0xF, 0xF, true);
}
__device__ __forceinline__ int x32(int x, unsigned lane){
  auto r = __builtin_amdgcn_permlane32_swap((unsigned)x, (unsigned)x, false, false);
  return (lane & 32u) ? (int)r[0] : (int)r[1];
}
template<int K>
__device__ __forceinline__ v2f xpart(v2f v, unsigned lane){
  int x0=__float_as_int(v[0]), x1=__float_as_int(v[1]);
  int y0, y1;
  if constexpr (K==0){ y0=dpp<0xB1>(x0);  y1=dpp<0xB1>(x1); }          // ^1 quad_perm
  else if constexpr (K==1){ y0=dpp<0x4E>(x0);  y1=dpp<0x4E>(x1); }     // ^2 quad_perm
  else if constexpr (K==2){                                            // ^4 ds_swizzle
    y0=__builtin_amdgcn_ds_swizzle(x0,0x101F);
    y1=__builtin_amdgcn_ds_swizzle(x1,0x101F);
  }
  else if constexpr (K==3){ y0=dpp<0x128>(x0); y1=dpp<0x128>(x1); }    // ^8 row_ror:8
  else if constexpr (K==4){                                            // ^16 ds_swizzle
    y0=__builtin_amdgcn_ds_swizzle(x0,0x401F);
    y1=__builtin_amdgcn_ds_swizzle(x1,0x401F);
  }
  else { y0=x32(x0,lane); y1=x32(x1,lane); }                           // ^32 permlane32
  v2f r; r[0]=__int_as_float(y0); r[1]=__int_as_float(y1); return r;
}

template<int BIT>
__device__ __forceinline__ void reg_gate(v2f (&a)[16], const GC& c, bool eps){
  v2f m00x=sel2(eps,c.u11x,c.u00x), m00n=sel2(eps,c.u11n,c.u00n);
  v2f m01x=sel2(eps,c.u10x,c.u01x), m01n=sel2(eps,c.u10n,c.u01n);
  v2f m10x=sel2(eps,c.u01x,c.u10x), m10n=sel2(eps,c.u01n,c.u10n);
  v2f m11x=sel2(eps,c.u00x,c.u11x), m11n=sel2(eps,c.u00n,c.u11n);
#pragma unroll
  for(int v=0; v<16; ++v){
    if(!((v>>BIT)&1)){
      int w = v | (1<<BIT);
      v2f a0=a[v], a1=a[w];
      a[v] = cfma_pk(m01x,m01n,a1, cmul_pk(m00x,m00n,a0));
      a[w] = cfma_pk(m11x,m11n,a1, cmul_pk(m10x,m10n,a0));
    }
  }
}

template<int XK, unsigned PI4>
__device__ __forceinline__ void lane_gate(v2f (&a)[16], const GC& c, bool sel, unsigned lane){
  v2f kax0=sel2(sel,c.u11x,c.u00x), kan0=sel2(sel,c.u11n,c.u00n);
  v2f kbx0=sel2(sel,c.u10x,c.u01x), kbn0=sel2(sel,c.u10n,c.u01n);
  v2f kax1=sel2(sel,c.u00x,c.u11x), kan1=sel2(sel,c.u00n,c.u11n);
  v2f kbx1=sel2(sel,c.u01x,c.u10x), kbn1=sel2(sel,c.u01n,c.u10n);
#pragma unroll
  for(int h=0;h<2;++h){
    v2f th[8];
#pragma unroll
    for(int jj=0;jj<8;++jj) th[jj] = xpart<XK>(a[h*8+jj], lane);
#pragma unroll
    for(int jj=0;jj<8;++jj){
      const int j = h*8+jj;
      bool pi = (__builtin_popcount(PI4 & (unsigned)j) & 1) != 0;
      v2f kax = pi?kax1:kax0, kan = pi?kan1:kan0;
      v2f kbx = pi?kbx1:kbx0, kbn = pi?kbn1:kbn0;
      a[j] = cfma_pk(kbx,kbn,th[jj], cmul_pk(kax,kan,a[j]));
    }
  }
}

// ---------------- the 3 chained kernels (templated on phase) ----------------
template<int PH>
__global__ __launch_bounds__(BLOCK, 2) void qk(
    const float* __restrict__ x, const float* __restrict__ prm,
    v2f* __restrict__ ws, float* __restrict__ out, int batch)
{
  __shared__ v2f    Utab[10*8];
  __shared__ float2 l0c[NQ][2];
  __shared__ float  red[NWAVES][NQ];

  const int bid = blockIdx.x;
  const int piece = (bid >= batch) ? 1 : 0;
  const int s = bid - piece*batch;
  const unsigned tid = threadIdx.x;
  const unsigned lane = tid & 63u;

  constexpr int NG = (PH==2) ? 8 : 10;
  if(tid < NG){
    int l = SL.lq[PH][tid][0], q = SL.lq[PH][tid][1];
    float ax=prm[(l*NQ+q)*3+0], ay=prm[(l*NQ+q)*3+1], az=prm[(l*NQ+q)*3+2];
    float cx,sx,cy,sy,cz,sz;
    sincosf(0.5f*ax,&sx,&cx); sincosf(0.5f*ay,&sy,&cy); sincosf(0.5f*az,&sz,&cz);
    float2 M00=make_float2(cy*cx, sy*sx),  M01=make_float2(-sy*cx,-cy*sx);
    float2 M10=make_float2(sy*cx,-cy*sx),  M11=make_float2(cy*cx,-sy*sx);
    float2 ez =make_float2(cz,-sz), ezc=make_float2(cz,sz);
    float2 U00=cmulf(ez,M00), U01=cmulf(ez,M01), U10=cmulf(ezc,M10), U11=cmulf(ezc,M11);
    v2f* U = &Utab[tid*8];
    U[0]=mkv(U00.x,U00.x); U[1]=mkv(-U00.y,U00.y);
    U[2]=mkv(U01.x,U01.x); U[3]=mkv(-U01.y,U01.y);
    U[4]=mkv(U10.x,U10.x); U[5]=mkv(-U10.y,U10.y);
    U[6]=mkv(U11.x,U11.x); U[7]=mkv(-U11.y,U11.y);
  }
  if constexpr (PH==0){
    if(tid < NQ){
      int q = tid;
      float ax = prm[q*3+0] + x[s*NQ+q];
      float ay = prm[q*3+1], az = prm[q*3+2];
      float cx,sx,cy,sy,cz,sz;
      sincosf(0.5f*ax,&sx,&cx); sincosf(0.5f*ay,&sy,&cy); sincosf(0.5f*az,&sz,&cz);
      l0c[q][0] = cmulf(make_float2(cz,-sz), make_float2(cy*cx,  sy*sx));   // U00
      l0c[q][1] = cmulf(make_float2(cz, sz), make_float2(sy*cx, -cy*sx));   // U10
    }
  }
  __syncthreads();

  // coset rep: free index e = wave (3b) | piece (1b), zeros inserted at the 10 pivots
  constexpr Ins  INS = (PH==0)?INS0:(PH==1)?INS1:INS2;
  constexpr CJ16 CJ  = (PH==0)?CJ0:(PH==1)?CJ1:CJ2;
  unsigned e = (tid>>6) | ((unsigned)piece<<3);
#pragma unroll
  for(int g=0; g<10; ++g) e = ((e & ~INS.ins[g])<<1) | (e & INS.ins[g]);
  unsigned s0t = e;
#pragma unroll
  for(int k=0;k<6;++k) s0t ^= SL.Gen[PH][4+k] & (0u - ((tid>>k)&1u));

  v2f* __restrict__ base = ws + (size_t)s*NST;

  v2f a[16];
  if constexpr (PH==0){
    // init: product state at each amp's physical index (layer 0 folded in)
#pragma unroll
    for(int j=0;j<16;++j){
      unsigned p = s0t ^ CJ.v[j];
      float2 acc = l0c[0][(p>>13)&1];
#pragma unroll
      for(int q=1;q<NQ;++q) acc = cmulf(acc, l0c[q][(p>>(13-q))&1]);
      a[j] = mkv(acc.x, acc.y);
    }
  } else {
#pragma unroll
    for(int j=0;j<16;++j) a[j] = base[s0t ^ CJ.v[j]];
  }

  // 4 reg gates (roles: runtime parity of row & base index; j-dependence is dual => j_b)
  reg_gate<0>(a, load_gc(Utab+0*8), (__builtin_popcount(SL.Row[PH][0]&s0t)&1)!=0);
  reg_gate<1>(a, load_gc(Utab+1*8), (__builtin_popcount(SL.Row[PH][1]&s0t)&1)!=0);
  reg_gate<2>(a, load_gc(Utab+2*8), (__builtin_popcount(SL.Row[PH][2]&s0t)&1)!=0);
  reg_gate<3>(a, load_gc(Utab+3*8), (__builtin_popcount(SL.Row[PH][3]&s0t)&1)!=0);
  // lane gates
  if constexpr (PH==0){
    lane_gate<0,0u>(a, load_gc(Utab+4*8), (__builtin_popcount(SL.Row[0][4]&s0t)&1)!=0, lane);
    lane_gate<1,0u>(a, load_gc(Utab+5*8), (__builtin_popcount(SL.Row[0][5]&s0t)&1)!=0, lane);
    lane_gate<2,0u>(a, load_gc(Utab+6*8), (__builtin_popcount(SL.Row[0][6]&s0t)&1)!=0, lane);
    lane_gate<3,0u>(a, load_gc(Utab+7*8), (__builtin_popcount(SL.Row[0][7]&s0t)&1)!=0, lane);
    lane_gate<4,0u>(a, load_gc(Utab+8*8), (__builtin_popcount(SL.Row[0][8]&s0t)&1)!=0, lane);
    lane_gate<5,0u>(a, load_gc(Utab+9*8), (__builtin_popcount(SL.Row[0][9]&s0t)&1)!=0, lane);
  } else if constexpr (PH==1){
    lane_gate<0,SL.BlanePi4[0]>(a, load_gc(Utab+4*8), (__builtin_popcount(SL.Row[1][4]&s0t)&1)!=0, lane);
    lane_gate<1,SL.BlanePi4[1]>(a, load_gc(Utab+5*8), (__builtin_popcount(SL.Row[1][5]&s0t)&1)!=0, lane);
    lane_gate<2,SL.BlanePi4[2]>(a, load_gc(Utab+6*8), (__builtin_popcount(SL.Row[1][6]&s0t)&1)!=0, lane);
    lane_gate<3,SL.BlanePi4[3]>(a, load_gc(Utab+7*8), (__builtin_popcount(SL.Row[1][7]&s0t)&1)!=0, lane);
    lane_gate<4,SL.BlanePi4[4]>(a, load_gc(Utab+8*8), (__builtin_popcount(SL.Row[1][8]&s0t)&1)!=0, lane);
    lane_gate<5,SL.BlanePi4[5]>(a, load_gc(Utab+9*8), (__builtin_popcount(SL.Row[1][9]&s0t)&1)!=0, lane);
  } else {
    lane_gate<0,0u>(a, load_gc(Utab+4*8), (__builtin_popcount(SL.Row[2][4]&s0t)&1)!=0, lane);
    lane_gate<1,0u>(a, load_gc(Utab+5*8), (__builtin_popcount(SL.Row[2][5]&s0t)&1)!=0, lane);
    lane_gate<2,0u>(a, load_gc(Utab+6*8), (__builtin_popcount(SL.Row[2][6]&s0t)&1)!=0, lane);
    lane_gate<3,0u>(a, load_gc(Utab+7*8), (__builtin_popcount(SL.Row[2][7]&s0t)&1)!=0, lane);
    // lane dims 4,5 are layout-only fillers: no gates
  }

  if constexpr (PH<2){
#pragma unroll
    for(int j=0;j<16;++j) base[s0t ^ CJ.v[j]] = a[j];
  } else {
    // expectation: sign_w(amp j) = parity(R_w & s0t) ^ parity(R_w & CJ[j])
    float acc[NQ];
#pragma unroll
    for(int w=0;w<NQ;++w) acc[w]=0.f;
#pragma unroll
    for(int j=0;j<16;++j){
      float p = a[j][0]*a[j][0] + a[j][1]*a[j][1];
#pragma unroll
      for(int w=0;w<NQ;++w){
        if(__builtin_popcount(SL.EJ4[w] & (unsigned)j) & 1) acc[w]-=p; else acc[w]+=p;
      }
    }
    const int wave = tid >> 6;
#pragma unroll
    for(int w=0;w<NQ;++w){
      float v = (__builtin_popcount(M3.row[NQ-1-w] & s0t)&1) ? -acc[w] : acc[w];
#pragma unroll
      for(int off=32; off>0; off>>=1) v += __shfl_down(v, off, 64);
      if(lane==0) red[wave][w]=v;
    }
    __syncthreads();
    if(tid < NQ){
      float t=0.f;
#pragma unroll
      for(int wv=0; wv<NWAVES; ++wv) t += red[wv][tid];
      atomicAdd(&out[s*NQ + tid], t);
    }
  }
}

}  // namespace

extern "C" void kernel_launch(void* const* d_in, const int* in_sizes, int n_in,
                              void* d_out, int out_size, void* d_ws, size_t ws_size,
                              hipStream_t stream) {
  const float* x   = (const float*)d_in[0];   // (batch, 14) f32
  const float* prm = (const float*)d_in[1];   // (3, 14, 3) f32
  float* out = (float*)d_out;                 // (batch, 14) f32
  const int batch = in_sizes[0] / NQ;
  v2f* ws = (v2f*)d_ws;                       // state: batch x 16384 float2 (16 MB @ batch=128)

  hipMemsetAsync(d_out, 0, (size_t)out_size*sizeof(float), stream);
  qk<0><<<2*batch, BLOCK, 0, stream>>>(x, prm, ws, out, batch);
  qk<1><<<2*batch, BLOCK, 0, stream>>>(x, prm, ws, out, batch);
  qk<2><<<2*batch, BLOCK, 0, stream>>>(x, prm, ws, out, batch);
}

// Round 10
// 40.757 us; speedup vs baseline: 1.3519x; 1.3519x over previous
//
#include <hip/hip_runtime.h>

namespace {

using v2f = __attribute__((ext_vector_type(2))) float;

constexpr int NQ      = 14;
constexpr int NSTATES = 1 << NQ;
constexpr int BLOCK   = 1024;
constexpr int NWAVES  = BLOCK / 64;

// ---------------- compile-time GF(2) machinery (verified R2-R8) ----------------
constexpr unsigned cparity(unsigned x){ x^=x>>8; x^=x>>4; x^=x>>2; x^=x>>1; return x&1u; }

struct Mat { unsigned row[NQ]; unsigned col[NQ]; };

constexpr Mat m_after(int nr){
  Mat m{};
  for(int p=0;p<NQ;++p){ m.row[p]=1u<<p; m.col[p]=1u<<p; }
  for(int l=0;l<nr;++l)
    for(int q=0;q<NQ;++q){
      int cq=(q==NQ-1)?NQ-1:q, tq=(q==NQ-1)?0:q+1;
      int Pc=NQ-1-cq, Pt=NQ-1-tq;
      m.row[Pt]^=m.row[Pc]; m.col[Pc]^=m.col[Pt];
    }
  return m;
}

constexpr Mat M1=m_after(1), M2=m_after(2), M3=m_after(3);
constexpr unsigned amask(int q){ return M1.col[NQ-1-q]; }
constexpr unsigned arow (int q){ return M1.row[NQ-1-q]; }
constexpr unsigned bmask(int q){ return M2.col[NQ-1-q]; }
constexpr unsigned brow (int q){ return M2.row[NQ-1-q]; }

constexpr int rank_of(const unsigned* v, int n){
  unsigned a[24]{};
  for(int i=0;i<n;++i) a[i]=v[i];
  int r=0;
  for(int bit=15;bit>=0;--bit){
    int p=-1;
    for(int i=r;i<n;++i){ if((a[i]>>bit)&1){ p=i; break; } }
    if(p<0) continue;
    unsigned t=a[r]; a[r]=a[p]; a[p]=t;
    for(int i=0;i<n;++i) if(i!=r && ((a[i]>>bit)&1)) a[i]^=a[r];
    ++r;
  }
  return r;
}

struct Plan {
  unsigned A[14], B[14], C[14];
  int BlaneGi[6]; unsigned BlanePi4[6];
  int BregGi[4];  unsigned BregEps[4];
  int CregGi[4];  unsigned CregEps[4];
  int ClaneGi[4]; unsigned ClaneEps[4];
  unsigned EJ4[14], ET[14];
};

constexpr Plan make_plan(){
  Plan P{};
  for(int t=0;t<14;++t) P.A[t]=amask(t);
  for(int t=0;t<4;++t){ P.B[t]=amask(10+t); P.BregGi[t]=10+t; }
  bool used[14]{}; int picked[14]{}; int np=0;
  {
    unsigned cur[20]{}; int nc=0;
    for(int t=0;t<4;++t) cur[nc++]=P.B[t];
    for(int q=0;q<14 && np<10;++q){
      cur[nc]=bmask(q);
      if(rank_of(cur,nc+1)==nc+1){ ++nc; picked[np++]=q; used[q]=true; }
    }
  }
  for(int i=0;i<6;++i){ P.B[4+i]=bmask(picked[i]); P.BlaneGi[i]=14+picked[i]; }
  int wq[4]{}, un[4]{}; int nu=0;
  for(int i=0;i<4;++i){ wq[i]=picked[6+i]; P.B[10+i]=bmask(wq[i]); P.CregGi[i]=14+wq[i]; }
  for(int q=0;q<14;++q) if(!used[q]) un[nu++]=q;
  for(int i=0;i<4;++i) P.ClaneGi[i]=14+un[i];
  for(int i=0;i<4;++i){ unsigned m=0;
    for(int t=0;t<10;++t) m |= cparity(arow(10+i)&P.B[4+t])<<t;
    P.BregEps[i]=m; }
  for(int i=0;i<6;++i){ unsigned m=0;
    for(int t=0;t<4;++t) m |= cparity(brow(picked[i])&P.B[t])<<t;
    P.BlanePi4[i]=m; }
  for(int t=0;t<4;++t) P.C[t]=bmask(wq[t]);
  for(int t=0;t<4;++t) P.C[4+t]=bmask(un[t]);
  {
    unsigned cc[20]{}; int n=0;
    for(int t=0;t<8;++t) cc[n++]=P.C[t];
    int pos=8;
    for(int p=0;p<14 && pos<14;++p){
      cc[n]=1u<<p;
      if(rank_of(cc,n+1)==n+1){ P.C[pos]=1u<<p; ++n; ++pos; }
    }
  }
  for(int i=0;i<4;++i){ unsigned m=0;
    for(int t=0;t<10;++t) m |= cparity(brow(wq[i])&P.C[4+t])<<t;
    P.CregEps[i]=m; }
  for(int i=0;i<4;++i){ unsigned m=0;
    for(int t=0;t<10;++t){ if(t==i) continue; m |= cparity(brow(un[i])&P.C[4+t])<<t; }
    P.ClaneEps[i]=m; }
  for(int w=0;w<14;++w){
    unsigned R=M3.row[NQ-1-w]; unsigned mj=0, mt=0;
    for(int t=0;t<4;++t)  mj |= cparity(R&P.C[t])<<t;
    for(int t=0;t<10;++t) mt |= cparity(R&P.C[4+t])<<t;
    P.EJ4[w]=mj; P.ET[w]=mt;
  }
  return P;
}

constexpr Plan PL = make_plan();
static_assert(rank_of(PL.A,14)==14, "phase A map not bijective");
static_assert(rank_of(PL.B,14)==14, "phase B map not bijective");
static_assert(rank_of(PL.C,14)==14, "phase C map not bijective");

// ---- basis inversion + phase transition matrices (all constexpr) ----
struct Inv { unsigned col[NQ]; };
constexpr Inv inv_basis(const unsigned* bas){
  unsigned vec[NQ]{}, cmb[NQ]{}; bool used[NQ]{}; int pivk[NQ]{};
  for(int k=0;k<NQ;++k){ vec[k]=bas[k]; cmb[k]=1u<<k; }
  for(int b=0;b<NQ;++b){
    int p=-1;
    for(int k=0;k<NQ;++k) if(!used[k] && ((vec[k]>>b)&1)){ p=k; break; }
    used[p]=true; pivk[b]=p;
    for(int k=0;k<NQ;++k) if(k!=p && ((vec[k]>>b)&1)){ vec[k]^=vec[p]; cmb[k]^=cmb[p]; }
  }
  Inv R{};
  for(int b=0;b<NQ;++b) R.col[b]=cmb[pivk[b]];
  return R;
}
constexpr bool check_inv(const unsigned* bas, const Inv& iv){
  for(int p=0;p<NQ;++p){
    unsigned s=0;
    for(int k=0;k<NQ;++k) if((iv.col[p]>>k)&1) s^=bas[k];
    if(s != (1u<<p)) return false;
  }
  return true;
}
constexpr Inv IA = inv_basis(PL.A), IB = inv_basis(PL.B), IC = inv_basis(PL.C);
static_assert(check_inv(PL.A, IA), "IA");
static_assert(check_inv(PL.B, IB), "IB");
static_assert(check_inv(PL.C, IC), "IC");

struct Trans { unsigned t[NQ]; };
constexpr Trans trans_phys(const Inv& iv){
  Trans T{};
  for(int p=0;p<NQ;++p) T.t[p]=iv.col[p];
  return T;
}
constexpr Trans trans_of(const unsigned* cur, const Inv& iv){
  Trans T{};
  for(int k=0;k<NQ;++k){
    unsigned c=0;
    for(int p=0;p<NQ;++p) if((cur[k]>>p)&1) c^=iv.col[p];
    T.t[k]=c;
  }
  return T;
}
constexpr Trans T_PA = trans_phys(IA);
constexpr Trans T_AB = trans_of(PL.A, IB);
constexpr Trans T_BC = trans_of(PL.B, IC);

struct CJ { unsigned v[16]; };
constexpr CJ mk_cj(const Trans& T){
  CJ c{};
  for(int j=0;j<16;++j){
    unsigned s=0;
    for(int b=0;b<4;++b) if((j>>b)&1) s^=T.t[b];
    c.v[j]=s;
  }
  return c;
}
constexpr CJ CJ_PA=mk_cj(T_PA), CJ_AB=mk_cj(T_AB), CJ_BC=mk_cj(T_BC);

// ---------------- packed-f32 complex helpers (verified) ----------------
__device__ __forceinline__ v2f mkv(float a, float b){ v2f r; r[0]=a; r[1]=b; return r; }

__device__ __forceinline__ v2f pk_mul(v2f a, v2f b){
  v2f d; asm("v_pk_mul_f32 %0, %1, %2 op_sel:[0,0] op_sel_hi:[1,1]" : "=v"(d) : "v"(a), "v"(b)); return d;
}
__device__ __forceinline__ v2f pk_fma(v2f a, v2f b, v2f c){
  v2f d; asm("v_pk_fma_f32 %0, %1, %2, %3 op_sel:[0,0,0] op_sel_hi:[1,1,1]" : "=v"(d) : "v"(a), "v"(b), "v"(c)); return d;
}
__device__ __forceinline__ v2f pk_fma_swap1(v2f a, v2f b, v2f c){
  v2f d; asm("v_pk_fma_f32 %0, %1, %2, %3 op_sel:[0,1,0] op_sel_hi:[1,0,1]" : "=v"(d) : "v"(a), "v"(b), "v"(c)); return d;
}
__device__ __forceinline__ v2f cmul_pk(v2f uxx, v2f uyn, v2f s){ return pk_fma_swap1(uyn, s, pk_mul(uxx, s)); }
__device__ __forceinline__ v2f cfma_pk(v2f uxx, v2f uyn, v2f s, v2f acc){ return pk_fma_swap1(uyn, s, pk_fma(uxx, s, acc)); }

__device__ __forceinline__ float2 cmulf(float2 a, float2 b){
  return make_float2(a.x*b.x - a.y*b.y, a.x*b.y + a.y*b.x);
}
__device__ __forceinline__ v2f sel2(bool c, v2f x, v2f y){ v2f r; r[0]=c?x[0]:y[0]; r[1]=c?x[1]:y[1]; return r; }

// gate constants loaded as 4x b128 (half the DS ops of 8x b64)
struct GC { v2f u00x,u00n,u01x,u01n,u10x,u10n,u11x,u11n; };
__device__ __forceinline__ GC load_gc(const v2f* __restrict__ g){
  const float4* p = reinterpret_cast<const float4*>(g);
  float4 q0=p[0], q1=p[1], q2=p[2], q3=p[3];
  GC c;
  c.u00x=mkv(q0.x,q0.y); c.u00n=mkv(q0.z,q0.w);
  c.u01x=mkv(q1.x,q1.y); c.u01n=mkv(q1.z,q1.w);
  c.u10x=mkv(q2.x,q2.y); c.u10n=mkv(q2.z,q2.w);
  c.u11x=mkv(q3.x,q3.y); c.u11n=mkv(q3.z,q3.w);
  return c;
}

// ---- lane exchange (partner value) ----
template<int CTRL>
__device__ __forceinline__ int dpp(int x){
  return __builtin_amdgcn_update_dpp(0, x, CTRL, 0xF, 0xF, true);
}
// ^32 via permlane32_swap (verified R7/R8)
__device__ __forceinline__ int x32(int x, unsigned lane){
  auto r = __builtin_amdgcn_permlane32_swap((unsigned)x, (unsigned)x, false, false);
  return (lane & 32u) ? (int)r[0] : (int)r[1];
}
// ^16 via permlane16_swap (same convention as verified permlane32), guarded
__device__ __forceinline__ int x16(int x, unsigned lane){
#if __has_builtin(__builtin_amdgcn_permlane16_swap)
  auto r = __builtin_amdgcn_permlane16_swap((unsigned)x, (unsigned)x, false, false);
  return (lane & 16u) ? (int)r[0] : (int)r[1];
#else
  return __builtin_amdgcn_ds_swizzle(x, 0x401F);
#endif
}
// K: 0:^1 1:^2 2:^4 3:^8 4:^16 5:^32
template<int K>
__device__ __forceinline__ v2f xpart(v2f v, unsigned lane){
  int x0=__float_as_int(v[0]), x1=__float_as_int(v[1]);
  int y0, y1;
  if constexpr (K==0){ y0=dpp<0xB1>(x0);  y1=dpp<0xB1>(x1); }          // ^1 quad_perm
  else if constexpr (K==1){ y0=dpp<0x4E>(x0);  y1=dpp<0x4E>(x1); }     // ^2 quad_perm
  else if constexpr (K==2){                                            // ^4 ds_swizzle (verified)
    y0=__builtin_amdgcn_ds_swizzle(x0,0x101F);
    y1=__builtin_amdgcn_ds_swizzle(x1,0x101F);
  }
  else if constexpr (K==3){ y0=dpp<0x128>(x0); y1=dpp<0x128>(x1); }    // ^8 row_ror:8 (verified)
  else if constexpr (K==4){ y0=x16(x0,lane); y1=x16(x1,lane); }        // ^16 permlane16
  else { y0=x32(x0,lane); y1=x32(x1,lane); }                           // ^32 permlane32 (verified)
  v2f r; r[0]=__int_as_float(y0); r[1]=__int_as_float(y1); return r;
}

template<int BIT>
__device__ __forceinline__ void reg_gate(v2f (&a)[16], const GC& c, bool eps){
  v2f m00x=sel2(eps,c.u11x,c.u00x), m00n=sel2(eps,c.u11n,c.u00n);
  v2f m01x=sel2(eps,c.u10x,c.u01x), m01n=sel2(eps,c.u10n,c.u01n);
  v2f m10x=sel2(eps,c.u01x,c.u10x), m10n=sel2(eps,c.u01n,c.u10n);
  v2f m11x=sel2(eps,c.u00x,c.u11x), m11n=sel2(eps,c.u00n,c.u11n);
#pragma unroll
  for(int v=0; v<16; ++v){
    if(!((v>>BIT)&1)){
      int w = v | (1<<BIT);
      v2f a0=a[v], a1=a[w];
      a[v] = cfma_pk(m01x,m01n,a1, cmul_pk(m00x,m00n,a0));
      a[w] = cfma_pk(m11x,m11n,a1, cmul_pk(m10x,m10n,a0));
    }
  }
}

// full-width batched lane gate: all 16 exchanges issued, then 16 updates
template<int XK, unsigned PI4>
__device__ __forceinline__ void lane_gate(v2f (&a)[16], const GC& c, bool sel, unsigned lane){
  v2f kax0=sel2(sel,c.u11x,c.u00x), kan0=sel2(sel,c.u11n,c.u00n);
  v2f kbx0=sel2(sel,c.u10x,c.u01x), kbn0=sel2(sel,c.u10n,c.u01n);
  v2f kax1=sel2(sel,c.u00x,c.u11x), kan1=sel2(sel,c.u00n,c.u11n);
  v2f kbx1=sel2(sel,c.u01x,c.u10x), kbn1=sel2(sel,c.u01n,c.u10n);
  v2f th[16];
#pragma unroll
  for(int j=0;j<16;++j) th[j] = xpart<XK>(a[j], lane);
#pragma unroll
  for(int j=0;j<16;++j){
    bool pi = (__builtin_popcount(PI4 & (unsigned)j) & 1) != 0;   // folds per unrolled j
    v2f kax = pi?kax1:kax0, kan = pi?kan1:kan0;
    v2f kbx = pi?kbx1:kbx0, kbn = pi?kbn1:kbn0;
    a[j] = cfma_pk(kbx,kbn,th[j], cmul_pk(kax,kan,a[j]));
  }
}

__device__ __forceinline__ unsigned nb_of(unsigned tid, const unsigned (&t)[NQ]){
  unsigned s=0;
#pragma unroll
  for(int k=0;k<10;++k) s ^= t[4+k] & (0u-((tid>>k)&1u));
  return s;
}

__device__ __forceinline__ void scatter16(v2f* __restrict__ st, const v2f (&a)[16],
                                          unsigned nb, const CJ& cj){
#pragma unroll
  for(int j=0;j<16;++j){
    unsigned d = nb ^ cj.v[j];
    st[d + (d>>4)] = a[j];
  }
}

// ---------------- kernel ----------------
__global__ __launch_bounds__(BLOCK, 4) void qsim_kernel(
    const float* __restrict__ x,
    const float* __restrict__ prm,
    float* __restrict__ out)
{
  __shared__ v2f    st[BLOCK*17];                // phase-ordered state (136 KiB)
  __shared__ alignas(16) v2f Utab[28*8];         // gate constants (layers 1,2)
  __shared__ float2 l0c[NQ][2];
  __shared__ float  red[NWAVES][NQ];

  const int b = blockIdx.x;
  const unsigned tid = threadIdx.x;
  const unsigned lane = tid & 63u;

  // ---- gate table built in-kernel ----
  if(tid < 28){
    int t = tid;
    int l = 1 + t/NQ, q = t % NQ;
    float ax=prm[(l*NQ+q)*3+0], ay=prm[(l*NQ+q)*3+1], az=prm[(l*NQ+q)*3+2];
    float cx,sx,cy,sy,cz,sz;
    sincosf(0.5f*ax,&sx,&cx); sincosf(0.5f*ay,&sy,&cy); sincosf(0.5f*az,&sz,&cz);
    float2 M00=make_float2(cy*cx, sy*sx),  M01=make_float2(-sy*cx,-cy*sx);
    float2 M10=make_float2(sy*cx,-cy*sx),  M11=make_float2(cy*cx,-sy*sx);
    float2 ez =make_float2(cz,-sz), ezc=make_float2(cz,sz);
    float2 U00=cmulf(ez,M00), U01=cmulf(ez,M01), U10=cmulf(ezc,M10), U11=cmulf(ezc,M11);
    v2f* U = &Utab[t*8];
    U[0]=mkv(U00.x,U00.x); U[1]=mkv(-U00.y,U00.y);
    U[2]=mkv(U01.x,U01.x); U[3]=mkv(-U01.y,U01.y);
    U[4]=mkv(U10.x,U10.x); U[5]=mkv(-U10.y,U10.y);
    U[6]=mkv(U11.x,U11.x); U[7]=mkv(-U11.y,U11.y);
  }
  // ---- layer-0 columns (x-dependent) ----
  if(tid < NQ){
    int q = tid;
    float ax = prm[q*3+0] + x[b*NQ+q];
    float ay = prm[q*3+1], az = prm[q*3+2];
    float cx,sx,cy,sy,cz,sz;
    sincosf(0.5f*ax,&sx,&cx); sincosf(0.5f*ay,&sy,&cy); sincosf(0.5f*az,&sz,&cz);
    l0c[q][0] = cmulf(make_float2(cz,-sz), make_float2(cy*cx,  sy*sx));   // U00
    l0c[q][1] = cmulf(make_float2(cz, sz), make_float2(sy*cx, -cy*sx));   // U10
  }
  __syncthreads();

  // ---- init: product state for s = (tid<<4)|j, scattered into phase-A layout ----
  {
    float2 Pk = l0c[0][(tid>>9)&1];
#pragma unroll
    for(int q=1;q<10;++q) Pk = cmulf(Pk, l0c[q][(tid>>(9-q))&1]);
    float2 t2[2], t4[4];
    t2[0]=cmulf(Pk,l0c[10][0]); t2[1]=cmulf(Pk,l0c[10][1]);
#pragma unroll
    for(int i=0;i<2;++i){ t4[2*i]=cmulf(t2[i],l0c[11][0]); t4[2*i+1]=cmulf(t2[i],l0c[11][1]); }
    v2f a[16];
#pragma unroll
    for(int j=0;j<16;++j){
      float2 v = cmulf(cmulf(t4[j>>2], l0c[12][(j>>1)&1]), l0c[13][j&1]);
      a[j] = mkv(v.x, v.y);
    }
    scatter16(st, a, nb_of(tid, T_PA.t), CJ_PA);
  }
  __syncthreads();

  // ---- phase A: 4 reg + 6 lane layer-1 gates (double-buffered const loads) ----
  {
    v2f a[16];
    const int rb = (int)tid*17;
#pragma unroll
    for(int j=0;j<16;++j) a[j] = st[rb + j];
    GC c0 = load_gc(Utab+0*8);
    GC c1 = load_gc(Utab+1*8);
    reg_gate<0>(a, c0, false);                 c0 = load_gc(Utab+2*8);
    reg_gate<1>(a, c1, false);                 c1 = load_gc(Utab+3*8);
    reg_gate<2>(a, c0, false);                 c0 = load_gc(Utab+4*8);
    reg_gate<3>(a, c1, false);                 c1 = load_gc(Utab+5*8);
    lane_gate<0,0u>(a, c0, (tid&1)!=0,  lane); c0 = load_gc(Utab+6*8);
    lane_gate<1,0u>(a, c1, (tid&2)!=0,  lane); c1 = load_gc(Utab+7*8);
    lane_gate<2,0u>(a, c0, (tid&4)!=0,  lane); c0 = load_gc(Utab+8*8);
    lane_gate<3,0u>(a, c1, (tid&8)!=0,  lane); c1 = load_gc(Utab+9*8);
    lane_gate<4,0u>(a, c0, (tid&16)!=0, lane);
    lane_gate<5,0u>(a, c1, (tid&32)!=0, lane);
    __syncthreads();                      // all reads done before cross-layout writes
    scatter16(st, a, nb_of(tid, T_AB.t), CJ_AB);
  }
  __syncthreads();

  // ---- phase B: 4 leftover layer-1 reg gates (runtime eps) + 6 layer-2 lane gates ----
  {
    v2f a[16];
    const int rb = (int)tid*17;
#pragma unroll
    for(int j=0;j<16;++j) a[j] = st[rb + j];
    GC c0 = load_gc(Utab+PL.BregGi[0]*8);
    GC c1 = load_gc(Utab+PL.BregGi[1]*8);
    reg_gate<0>(a, c0, (__builtin_popcount(PL.BregEps[0]&tid)&1)!=0); c0 = load_gc(Utab+PL.BregGi[2]*8);
    reg_gate<1>(a, c1, (__builtin_popcount(PL.BregEps[1]&tid)&1)!=0); c1 = load_gc(Utab+PL.BregGi[3]*8);
    reg_gate<2>(a, c0, (__builtin_popcount(PL.BregEps[2]&tid)&1)!=0); c0 = load_gc(Utab+PL.BlaneGi[0]*8);
    reg_gate<3>(a, c1, (__builtin_popcount(PL.BregEps[3]&tid)&1)!=0); c1 = load_gc(Utab+PL.BlaneGi[1]*8);
    lane_gate<0,PL.BlanePi4[0]>(a, c0, (tid&1)!=0,  lane);            c0 = load_gc(Utab+PL.BlaneGi[2]*8);
    lane_gate<1,PL.BlanePi4[1]>(a, c1, (tid&2)!=0,  lane);            c1 = load_gc(Utab+PL.BlaneGi[3]*8);
    lane_gate<2,PL.BlanePi4[2]>(a, c0, (tid&4)!=0,  lane);            c0 = load_gc(Utab+PL.BlaneGi[4]*8);
    lane_gate<3,PL.BlanePi4[3]>(a, c1, (tid&8)!=0,  lane);            c1 = load_gc(Utab+PL.BlaneGi[5]*8);
    lane_gate<4,PL.BlanePi4[4]>(a, c0, (tid&16)!=0, lane);
    lane_gate<5,PL.BlanePi4[5]>(a, c1, (tid&32)!=0, lane);
    __syncthreads();
    scatter16(st, a, nb_of(tid, T_BC.t), CJ_BC);
  }
  __syncthreads();

  // ---- phase C: last 8 layer-2 gates, expectation from registers ----
  {
    v2f a[16];
    const int rb = (int)tid*17;
#pragma unroll
    for(int j=0;j<16;++j) a[j] = st[rb + j];
    GC c0 = load_gc(Utab+PL.CregGi[0]*8);
    GC c1 = load_gc(Utab+PL.CregGi[1]*8);
    reg_gate<0>(a, c0, (__builtin_popcount(PL.CregEps[0]&tid)&1)!=0); c0 = load_gc(Utab+PL.CregGi[2]*8);
    reg_gate<1>(a, c1, (__builtin_popcount(PL.CregEps[1]&tid)&1)!=0); c1 = load_gc(Utab+PL.CregGi[3]*8);
    reg_gate<2>(a, c0, (__builtin_popcount(PL.CregEps[2]&tid)&1)!=0); c0 = load_gc(Utab+PL.ClaneGi[0]*8);
    reg_gate<3>(a, c1, (__builtin_popcount(PL.CregEps[3]&tid)&1)!=0); c1 = load_gc(Utab+PL.ClaneGi[1]*8);
    lane_gate<0,0u>(a, c0,
        (((tid&1u)!=0) != ((__builtin_popcount(PL.ClaneEps[0]&tid)&1)!=0)), lane);
    c0 = load_gc(Utab+PL.ClaneGi[2]*8);
    lane_gate<1,0u>(a, c1,
        (((tid&2u)!=0) != ((__builtin_popcount(PL.ClaneEps[1]&tid)&1)!=0)), lane);
    c1 = load_gc(Utab+PL.ClaneGi[3]*8);
    lane_gate<2,0u>(a, c0,
        (((tid&4u)!=0) != ((__builtin_popcount(PL.ClaneEps[2]&tid)&1)!=0)), lane);
    lane_gate<3,0u>(a, c1,
        (((tid&8u)!=0) != ((__builtin_popcount(PL.ClaneEps[3]&tid)&1)!=0)), lane);

    float acc[NQ];
#pragma unroll
    for(int w=0;w<NQ;++w) acc[w]=0.f;
#pragma unroll
    for(int j=0;j<16;++j){
      float p = a[j][0]*a[j][0] + a[j][1]*a[j][1];
#pragma unroll
      for(int w=0;w<NQ;++w){
        if(__builtin_popcount(PL.EJ4[w] & (unsigned)j) & 1) acc[w]-=p; else acc[w]+=p;
      }
    }
    const int wave = tid >> 6;
#pragma unroll
    for(int w=0;w<NQ;++w){
      float v = (__builtin_popcount(PL.ET[w]&tid)&1) ? -acc[w] : acc[w];
#pragma unroll
      for(int off=32; off>0; off>>=1) v += __shfl_down(v, off, 64);
      if(lane==0) red[wave][w]=v;
    }
    __syncthreads();
    if(tid < NQ){
      float s=0.f;
#pragma unroll
      for(int wv=0; wv<NWAVES; ++wv) s += red[wv][tid];
      out[b*NQ + tid] = s;
    }
  }
}

}  // namespace

extern "C" void kernel_launch(void* const* d_in, const int* in_sizes, int n_in,
                              void* d_out, int out_size, void* d_ws, size_t ws_size,
                              hipStream_t stream) {
  const float* x   = (const float*)d_in[0];   // (batch, 14) f32
  const float* prm = (const float*)d_in[1];   // (3, 14, 3) f32
  float* out = (float*)d_out;                 // (batch, 14) f32
  const int batch = in_sizes[0] / NQ;
  qsim_kernel<<<batch, BLOCK, 0, stream>>>(x, prm, out);
}

// Round 11
// 37.967 us; speedup vs baseline: 1.4513x; 1.0735x over previous
//
#include <hip/hip_runtime.h>

namespace {

constexpr int NQ      = 14;
constexpr int NSTATES = 1 << NQ;
constexpr int BLOCK   = 1024;
constexpr int NWAVES  = BLOCK / 64;

// ---------------- compile-time GF(2) machinery (verified R2-R10) ----------------
constexpr unsigned cparity(unsigned x){ x^=x>>8; x^=x>>4; x^=x>>2; x^=x>>1; return x&1u; }

struct Mat { unsigned row[NQ]; unsigned col[NQ]; };

constexpr Mat m_after(int nr){
  Mat m{};
  for(int p=0;p<NQ;++p){ m.row[p]=1u<<p; m.col[p]=1u<<p; }
  for(int l=0;l<nr;++l)
    for(int q=0;q<NQ;++q){
      int cq=(q==NQ-1)?NQ-1:q, tq=(q==NQ-1)?0:q+1;
      int Pc=NQ-1-cq, Pt=NQ-1-tq;
      m.row[Pt]^=m.row[Pc]; m.col[Pc]^=m.col[Pt];
    }
  return m;
}

constexpr Mat M1=m_after(1), M2=m_after(2), M3=m_after(3);
constexpr unsigned amask(int q){ return M1.col[NQ-1-q]; }
constexpr unsigned arow (int q){ return M1.row[NQ-1-q]; }
constexpr unsigned bmask(int q){ return M2.col[NQ-1-q]; }
constexpr unsigned brow (int q){ return M2.row[NQ-1-q]; }

constexpr int rank_of(const unsigned* v, int n){
  unsigned a[24]{};
  for(int i=0;i<n;++i) a[i]=v[i];
  int r=0;
  for(int bit=15;bit>=0;--bit){
    int p=-1;
    for(int i=r;i<n;++i){ if((a[i]>>bit)&1){ p=i; break; } }
    if(p<0) continue;
    unsigned t=a[r]; a[r]=a[p]; a[p]=t;
    for(int i=0;i<n;++i) if(i!=r && ((a[i]>>bit)&1)) a[i]^=a[r];
    ++r;
  }
  return r;
}

struct Plan {
  unsigned A[14], B[14], C[14];
  int BlaneGi[6]; unsigned BlanePi4[6];
  int BregGi[4];  unsigned BregEps[4];
  int CregGi[4];  unsigned CregEps[4];
  int ClaneGi[4]; unsigned ClaneEps[4];
  unsigned EJ4[14], ET[14];
};

constexpr Plan make_plan(){
  Plan P{};
  for(int t=0;t<14;++t) P.A[t]=amask(t);
  for(int t=0;t<4;++t){ P.B[t]=amask(10+t); P.BregGi[t]=10+t; }
  bool used[14]{}; int picked[14]{}; int np=0;
  {
    unsigned cur[20]{}; int nc=0;
    for(int t=0;t<4;++t) cur[nc++]=P.B[t];
    for(int q=0;q<14 && np<10;++q){
      cur[nc]=bmask(q);
      if(rank_of(cur,nc+1)==nc+1){ ++nc; picked[np++]=q; used[q]=true; }
    }
  }
  for(int i=0;i<6;++i){ P.B[4+i]=bmask(picked[i]); P.BlaneGi[i]=14+picked[i]; }
  int wq[4]{}, un[4]{}; int nu=0;
  for(int i=0;i<4;++i){ wq[i]=picked[6+i]; P.B[10+i]=bmask(wq[i]); P.CregGi[i]=14+wq[i]; }
  for(int q=0;q<14;++q) if(!used[q]) un[nu++]=q;
  for(int i=0;i<4;++i) P.ClaneGi[i]=14+un[i];
  for(int i=0;i<4;++i){ unsigned m=0;
    for(int t=0;t<10;++t) m |= cparity(arow(10+i)&P.B[4+t])<<t;
    P.BregEps[i]=m; }
  for(int i=0;i<6;++i){ unsigned m=0;
    for(int t=0;t<4;++t) m |= cparity(brow(picked[i])&P.B[t])<<t;
    P.BlanePi4[i]=m; }
  for(int t=0;t<4;++t) P.C[t]=bmask(wq[t]);
  for(int t=0;t<4;++t) P.C[4+t]=bmask(un[t]);
  {
    unsigned cc[20]{}; int n=0;
    for(int t=0;t<8;++t) cc[n++]=P.C[t];
    int pos=8;
    for(int p=0;p<14 && pos<14;++p){
      cc[n]=1u<<p;
      if(rank_of(cc,n+1)==n+1){ P.C[pos]=1u<<p; ++n; ++pos; }
    }
  }
  for(int i=0;i<4;++i){ unsigned m=0;
    for(int t=0;t<10;++t) m |= cparity(brow(wq[i])&P.C[4+t])<<t;
    P.CregEps[i]=m; }
  for(int i=0;i<4;++i){ unsigned m=0;
    for(int t=0;t<10;++t){ if(t==i) continue; m |= cparity(brow(un[i])&P.C[4+t])<<t; }
    P.ClaneEps[i]=m; }
  for(int w=0;w<14;++w){
    unsigned R=M3.row[NQ-1-w]; unsigned mj=0, mt=0;
    for(int t=0;t<4;++t)  mj |= cparity(R&P.C[t])<<t;
    for(int t=0;t<10;++t) mt |= cparity(R&P.C[4+t])<<t;
    P.EJ4[w]=mj; P.ET[w]=mt;
  }
  return P;
}

constexpr Plan PL = make_plan();
static_assert(rank_of(PL.A,14)==14, "phase A map not bijective");
static_assert(rank_of(PL.B,14)==14, "phase B map not bijective");
static_assert(rank_of(PL.C,14)==14, "phase C map not bijective");

struct Inv { unsigned col[NQ]; };
constexpr Inv inv_basis(const unsigned* bas){
  unsigned vec[NQ]{}, cmb[NQ]{}; bool used[NQ]{}; int pivk[NQ]{};
  for(int k=0;k<NQ;++k){ vec[k]=bas[k]; cmb[k]=1u<<k; }
  for(int b=0;b<NQ;++b){
    int p=-1;
    for(int k=0;k<NQ;++k) if(!used[k] && ((vec[k]>>b)&1)){ p=k; break; }
    used[p]=true; pivk[b]=p;
    for(int k=0;k<NQ;++k) if(k!=p && ((vec[k]>>b)&1)){ vec[k]^=vec[p]; cmb[k]^=cmb[p]; }
  }
  Inv R{};
  for(int b=0;b<NQ;++b) R.col[b]=cmb[pivk[b]];
  return R;
}
constexpr bool check_inv(const unsigned* bas, const Inv& iv){
  for(int p=0;p<NQ;++p){
    unsigned s=0;
    for(int k=0;k<NQ;++k) if((iv.col[p]>>k)&1) s^=bas[k];
    if(s != (1u<<p)) return false;
  }
  return true;
}
constexpr Inv IA = inv_basis(PL.A), IB = inv_basis(PL.B), IC = inv_basis(PL.C);
static_assert(check_inv(PL.A, IA), "IA");
static_assert(check_inv(PL.B, IB), "IB");
static_assert(check_inv(PL.C, IC), "IC");

struct Trans { unsigned t[NQ]; };
constexpr Trans trans_phys(const Inv& iv){
  Trans T{};
  for(int p=0;p<NQ;++p) T.t[p]=iv.col[p];
  return T;
}
constexpr Trans trans_of(const unsigned* cur, const Inv& iv){
  Trans T{};
  for(int k=0;k<NQ;++k){
    unsigned c=0;
    for(int p=0;p<NQ;++p) if((cur[k]>>p)&1) c^=iv.col[p];
    T.t[k]=c;
  }
  return T;
}
constexpr Trans T_PA = trans_phys(IA);
constexpr Trans T_AB = trans_of(PL.A, IB);
constexpr Trans T_BC = trans_of(PL.B, IC);

struct CJ { unsigned v[16]; };
constexpr CJ mk_cj(const Trans& T){
  CJ c{};
  for(int j=0;j<16;++j){
    unsigned s=0;
    for(int b=0;b<4;++b) if((j>>b)&1) s^=T.t[b];
    c.v[j]=s;
  }
  return c;
}
constexpr CJ CJ_PA=mk_cj(T_PA), CJ_AB=mk_cj(T_AB), CJ_BC=mk_cj(T_BC);

// ---------------- plain float2 complex helpers (compiler-schedulable) ----------------
__device__ __forceinline__ float2 cmul2(float2 a, float2 b){
  return make_float2(fmaf(a.x, b.x, -(a.y * b.y)),
                     fmaf(a.x, b.y,  a.y * b.x));
}
__device__ __forceinline__ float2 cfma2(float2 a, float2 b, float2 c){  // c + a*b
  return make_float2(fmaf(a.x, b.x, fmaf(-a.y, b.y, c.x)),
                     fmaf(a.x, b.y, fmaf( a.y, b.x, c.y)));
}
__device__ __forceinline__ float2 sel2f(bool c, float2 x, float2 y){
  return make_float2(c ? x.x : y.x, c ? x.y : y.y);
}

// gate constants: U00,U01,U10,U11 as float2 (2x b128 loads per gate)
struct GC { float2 u00,u01,u10,u11; };
__device__ __forceinline__ GC load_gc(const float2* __restrict__ g){
  const float4* p = reinterpret_cast<const float4*>(g);
  float4 q0=p[0], q1=p[1];
  GC c;
  c.u00=make_float2(q0.x,q0.y); c.u01=make_float2(q0.z,q0.w);
  c.u10=make_float2(q1.x,q1.y); c.u11=make_float2(q1.z,q1.w);
  return c;
}

// ---- lane exchange (all variants HW-verified in passing builds) ----
template<int CTRL>
__device__ __forceinline__ int dpp(int x){
  return __builtin_amdgcn_update_dpp(0, x, CTRL, 0xF, 0xF, true);
}
__device__ __forceinline__ int x32(int x, unsigned lane){
  auto r = __builtin_amdgcn_permlane32_swap((unsigned)x, (unsigned)x, false, false);
  return (lane & 32u) ? (int)r[0] : (int)r[1];
}
// K: 0:^1 1:^2 2:^4 3:^8 4:^16 5:^32
template<int K>
__device__ __forceinline__ float2 xpart(float2 v, unsigned lane){
  int x0=__float_as_int(v.x), x1=__float_as_int(v.y);
  int y0, y1;
  if constexpr (K==0){ y0=dpp<0xB1>(x0);  y1=dpp<0xB1>(x1); }          // ^1 quad_perm
  else if constexpr (K==1){ y0=dpp<0x4E>(x0);  y1=dpp<0x4E>(x1); }     // ^2 quad_perm
  else if constexpr (K==2){                                            // ^4 ds_swizzle
    y0=__builtin_amdgcn_ds_swizzle(x0,0x101F);
    y1=__builtin_amdgcn_ds_swizzle(x1,0x101F);
  }
  else if constexpr (K==3){ y0=dpp<0x128>(x0); y1=dpp<0x128>(x1); }    // ^8 row_ror:8
  else if constexpr (K==4){                                            // ^16 ds_swizzle
    y0=__builtin_amdgcn_ds_swizzle(x0,0x401F);
    y1=__builtin_amdgcn_ds_swizzle(x1,0x401F);
  }
  else { y0=x32(x0,lane); y1=x32(x1,lane); }                           // ^32 permlane32
  return make_float2(__int_as_float(y0), __int_as_float(y1));
}

template<int BIT>
__device__ __forceinline__ void reg_gate(float2 (&a)[16], const GC& c, bool eps){
  float2 m00=sel2f(eps,c.u11,c.u00), m01=sel2f(eps,c.u10,c.u01);
  float2 m10=sel2f(eps,c.u01,c.u10), m11=sel2f(eps,c.u00,c.u11);
#pragma unroll
  for(int v=0; v<16; ++v){
    if(!((v>>BIT)&1)){
      int w = v | (1<<BIT);
      float2 a0=a[v], a1=a[w];
      a[v] = cfma2(m01, a1, cmul2(m00, a0));
      a[w] = cfma2(m11, a1, cmul2(m10, a0));
    }
  }
}

// batched lane gate: all 16 exchanges issued, then 16 independent updates
template<int XK, unsigned PI4>
__device__ __forceinline__ void lane_gate(float2 (&a)[16], const GC& c, bool sel, unsigned lane){
  float2 ka0=sel2f(sel,c.u11,c.u00), kb0=sel2f(sel,c.u10,c.u01);
  float2 ka1=sel2f(sel,c.u00,c.u11), kb1=sel2f(sel,c.u01,c.u10);
  float2 th[16];
#pragma unroll
  for(int j=0;j<16;++j) th[j] = xpart<XK>(a[j], lane);
#pragma unroll
  for(int j=0;j<16;++j){
    bool pi = (__builtin_popcount(PI4 & (unsigned)j) & 1) != 0;   // folds per unrolled j
    float2 ka = pi?ka1:ka0, kb = pi?kb1:kb0;
    a[j] = cfma2(kb, th[j], cmul2(ka, a[j]));
  }
}

__device__ __forceinline__ unsigned nb_of(unsigned tid, const unsigned (&t)[NQ]){
  unsigned s=0;
#pragma unroll
  for(int k=0;k<10;++k) s ^= t[4+k] & (0u-((tid>>k)&1u));
  return s;
}

__device__ __forceinline__ void scatter16(float2* __restrict__ st, const float2 (&a)[16],
                                          unsigned nb, const CJ& cj){
#pragma unroll
  for(int j=0;j<16;++j){
    unsigned d = nb ^ cj.v[j];
    st[d + (d>>4)] = a[j];
  }
}

// ---------------- kernel ----------------
__global__ __launch_bounds__(BLOCK, 4) void qsim_kernel(
    const float* __restrict__ x,
    const float* __restrict__ prm,
    float* __restrict__ out)
{
  __shared__ float2 st[BLOCK*17];                // phase-ordered state (136 KiB)
  __shared__ alignas(16) float2 Utab[28*4];      // gate constants (layers 1,2)
  __shared__ float2 l0c[NQ][2];
  __shared__ float  red[NWAVES][NQ];

  const int b = blockIdx.x;
  const unsigned tid = threadIdx.x;
  const unsigned lane = tid & 63u;

  // ---- gate table built in-kernel ----
  if(tid < 28){
    int t = tid;
    int l = 1 + t/NQ, q = t % NQ;
    float ax=prm[(l*NQ+q)*3+0], ay=prm[(l*NQ+q)*3+1], az=prm[(l*NQ+q)*3+2];
    float cx,sx,cy,sy,cz,sz;
    sincosf(0.5f*ax,&sx,&cx); sincosf(0.5f*ay,&sy,&cy); sincosf(0.5f*az,&sz,&cz);
    float2 M00=make_float2(cy*cx, sy*sx),  M01=make_float2(-sy*cx,-cy*sx);
    float2 M10=make_float2(sy*cx,-cy*sx),  M11=make_float2(cy*cx,-sy*sx);
    float2 ez =make_float2(cz,-sz), ezc=make_float2(cz,sz);
    float2* U = &Utab[t*4];
    U[0]=cmul2(ez,M00); U[1]=cmul2(ez,M01);
    U[2]=cmul2(ezc,M10); U[3]=cmul2(ezc,M11);
  }
  // ---- layer-0 columns (x-dependent) ----
  if(tid < NQ){
    int q = tid;
    float ax = prm[q*3+0] + x[b*NQ+q];
    float ay = prm[q*3+1], az = prm[q*3+2];
    float cx,sx,cy,sy,cz,sz;
    sincosf(0.5f*ax,&sx,&cx); sincosf(0.5f*ay,&sy,&cy); sincosf(0.5f*az,&sz,&cz);
    l0c[q][0] = cmul2(make_float2(cz,-sz), make_float2(cy*cx,  sy*sx));   // U00
    l0c[q][1] = cmul2(make_float2(cz, sz), make_float2(sy*cx, -cy*sx));   // U10
  }
  __syncthreads();

  // ---- init: product state for s = (tid<<4)|j, scattered into phase-A layout ----
  {
    // balanced tree over the 10 tid-qubits
    float2 p01 = cmul2(l0c[0][(tid>>9)&1],  l0c[1][(tid>>8)&1]);
    float2 p23 = cmul2(l0c[2][(tid>>7)&1],  l0c[3][(tid>>6)&1]);
    float2 p45 = cmul2(l0c[4][(tid>>5)&1],  l0c[5][(tid>>4)&1]);
    float2 p67 = cmul2(l0c[6][(tid>>3)&1],  l0c[7][(tid>>2)&1]);
    float2 p89 = cmul2(l0c[8][(tid>>1)&1],  l0c[9][tid&1]);
    float2 Pk  = cmul2(cmul2(cmul2(p01,p23), cmul2(p45,p67)), p89);
    float2 t2[2], t4[4];
    t2[0]=cmul2(Pk,l0c[10][0]); t2[1]=cmul2(Pk,l0c[10][1]);
#pragma unroll
    for(int i=0;i<2;++i){ t4[2*i]=cmul2(t2[i],l0c[11][0]); t4[2*i+1]=cmul2(t2[i],l0c[11][1]); }
    float2 a[16];
#pragma unroll
    for(int j=0;j<16;++j){
      a[j] = cmul2(cmul2(t4[j>>2], l0c[12][(j>>1)&1]), l0c[13][j&1]);
    }
    scatter16(st, a, nb_of(tid, T_PA.t), CJ_PA);
  }
  __syncthreads();

  // ---- phase A: 4 reg + 6 lane layer-1 gates ----
  {
    float2 a[16];
    const int rb = (int)tid*17;
#pragma unroll
    for(int j=0;j<16;++j) a[j] = st[rb + j];
    reg_gate<0>(a, load_gc(Utab+0*4), false);
    reg_gate<1>(a, load_gc(Utab+1*4), false);
    reg_gate<2>(a, load_gc(Utab+2*4), false);
    reg_gate<3>(a, load_gc(Utab+3*4), false);
    lane_gate<0,0u>(a, load_gc(Utab+4*4), (tid&1)!=0,  lane);
    lane_gate<1,0u>(a, load_gc(Utab+5*4), (tid&2)!=0,  lane);
    lane_gate<2,0u>(a, load_gc(Utab+6*4), (tid&4)!=0,  lane);
    lane_gate<3,0u>(a, load_gc(Utab+7*4), (tid&8)!=0,  lane);
    lane_gate<4,0u>(a, load_gc(Utab+8*4), (tid&16)!=0, lane);
    lane_gate<5,0u>(a, load_gc(Utab+9*4), (tid&32)!=0, lane);
    __syncthreads();                      // all reads done before cross-layout writes
    scatter16(st, a, nb_of(tid, T_AB.t), CJ_AB);
  }
  __syncthreads();

  // ---- phase B: 4 leftover layer-1 reg gates (runtime eps) + 6 layer-2 lane gates ----
  {
    float2 a[16];
    const int rb = (int)tid*17;
#pragma unroll
    for(int j=0;j<16;++j) a[j] = st[rb + j];
    reg_gate<0>(a, load_gc(Utab+PL.BregGi[0]*4), (__builtin_popcount(PL.BregEps[0]&tid)&1)!=0);
    reg_gate<1>(a, load_gc(Utab+PL.BregGi[1]*4), (__builtin_popcount(PL.BregEps[1]&tid)&1)!=0);
    reg_gate<2>(a, load_gc(Utab+PL.BregGi[2]*4), (__builtin_popcount(PL.BregEps[2]&tid)&1)!=0);
    reg_gate<3>(a, load_gc(Utab+PL.BregGi[3]*4), (__builtin_popcount(PL.BregEps[3]&tid)&1)!=0);
    lane_gate<0,PL.BlanePi4[0]>(a, load_gc(Utab+PL.BlaneGi[0]*4), (tid&1)!=0,  lane);
    lane_gate<1,PL.BlanePi4[1]>(a, load_gc(Utab+PL.BlaneGi[1]*4), (tid&2)!=0,  lane);
    lane_gate<2,PL.BlanePi4[2]>(a, load_gc(Utab+PL.BlaneGi[2]*4), (tid&4)!=0,  lane);
    lane_gate<3,PL.BlanePi4[3]>(a, load_gc(Utab+PL.BlaneGi[3]*4), (tid&8)!=0,  lane);
    lane_gate<4,PL.BlanePi4[4]>(a, load_gc(Utab+PL.BlaneGi[4]*4), (tid&16)!=0, lane);
    lane_gate<5,PL.BlanePi4[5]>(a, load_gc(Utab+PL.BlaneGi[5]*4), (tid&32)!=0, lane);
    __syncthreads();
    scatter16(st, a, nb_of(tid, T_BC.t), CJ_BC);
  }
  __syncthreads();

  // ---- phase C: last 8 layer-2 gates, expectation from registers ----
  {
    float2 a[16];
    const int rb = (int)tid*17;
#pragma unroll
    for(int j=0;j<16;++j) a[j] = st[rb + j];
    reg_gate<0>(a, load_gc(Utab+PL.CregGi[0]*4), (__builtin_popcount(PL.CregEps[0]&tid)&1)!=0);
    reg_gate<1>(a, load_gc(Utab+PL.CregGi[1]*4), (__builtin_popcount(PL.CregEps[1]&tid)&1)!=0);
    reg_gate<2>(a, load_gc(Utab+PL.CregGi[2]*4), (__builtin_popcount(PL.CregEps[2]&tid)&1)!=0);
    reg_gate<3>(a, load_gc(Utab+PL.CregGi[3]*4), (__builtin_popcount(PL.CregEps[3]&tid)&1)!=0);
    lane_gate<0,0u>(a, load_gc(Utab+PL.ClaneGi[0]*4),
        (((tid&1u)!=0) != ((__builtin_popcount(PL.ClaneEps[0]&tid)&1)!=0)), lane);
    lane_gate<1,0u>(a, load_gc(Utab+PL.ClaneGi[1]*4),
        (((tid&2u)!=0) != ((__builtin_popcount(PL.ClaneEps[1]&tid)&1)!=0)), lane);
    lane_gate<2,0u>(a, load_gc(Utab+PL.ClaneGi[2]*4),
        (((tid&4u)!=0) != ((__builtin_popcount(PL.ClaneEps[2]&tid)&1)!=0)), lane);
    lane_gate<3,0u>(a, load_gc(Utab+PL.ClaneGi[3]*4),
        (((tid&8u)!=0) != ((__builtin_popcount(PL.ClaneEps[3]&tid)&1)!=0)), lane);

    // ---- expectation via 4-bit Walsh-Hadamard: s[m] = sum_j (-1)^{popc(m&j)} p[j] ----
    float p[16];
#pragma unroll
    for(int j=0;j<16;++j) p[j] = a[j].x*a[j].x + a[j].y*a[j].y;
#pragma unroll
    for(int bstep=1; bstep<16; bstep<<=1){
#pragma unroll
      for(int j=0;j<16;++j){
        if(!(j & bstep)){
          float u = p[j], v = p[j|bstep];
          p[j] = u + v;
          p[j|bstep] = u - v;
        }
      }
    }
    const int wave = tid >> 6;
#pragma unroll
    for(int w=0;w<NQ;++w){
      float v = (__builtin_popcount(PL.ET[w]&tid)&1) ? -p[PL.EJ4[w]] : p[PL.EJ4[w]];
#pragma unroll
      for(int off=32; off>0; off>>=1) v += __shfl_down(v, off, 64);
      if(lane==0) red[wave][w]=v;
    }
    __syncthreads();
    if(tid < NQ){
      float s=0.f;
#pragma unroll
      for(int wv=0; wv<NWAVES; ++wv) s += red[wv][tid];
      out[b*NQ + tid] = s;
    }
  }
}

}  // namespace

extern "C" void kernel_launch(void* const* d_in, const int* in_sizes, int n_in,
                              void* d_out, int out_size, void* d_ws, size_t ws_size,
                              hipStream_t stream) {
  const float* x   = (const float*)d_in[0];   // (batch, 14) f32
  const float* prm = (const float*)d_in[1];   // (3, 14, 3) f32
  float* out = (float*)d_out;                 // (batch, 14) f32
  const int batch = in_sizes[0] / NQ;
  qsim_kernel<<<batch, BLOCK, 0, stream>>>(x, prm, out);
}